// Round 4
// baseline (302.947 us; speedup 1.0000x reference)
//
#include <hip/hip_runtime.h>
#include <math.h>

#define NN 4096
#define DIMV 256
#define ECAP 768   // max edges/row; Binomial(4096,0.05): mean 205, sd 14

// ---------------------------------------------------------------------------
// fp32 GEMM: C = A @ W^T + bias (+resid). A:[M,256], W:[256,256] row-major.
// Tile 128x128, BK=16, 256 threads, 8x8 microtile per thread.
// ---------------------------------------------------------------------------
__device__ __forceinline__ void gemm_body(
    const float* __restrict__ A, const float* __restrict__ W,
    const float* __restrict__ bias, const float* __restrict__ resid,
    float* __restrict__ C, int mb, int nb)
{
    __shared__ float As[16][132];
    __shared__ float Bs[16][132];
    const int tid = threadIdx.x;
    const int tx = tid & 15, ty = tid >> 4;
    const int row0 = mb * 128, col0 = nb * 128;
    const int lr = tid >> 2;          // 0..63
    const int lc = (tid & 3) * 4;     // 0,4,8,12

    float acc[8][8] = {};

    for (int k0 = 0; k0 < 256; k0 += 16) {
        const float4 a0 = *(const float4*)(A + (size_t)(row0 + lr) * 256 + k0 + lc);
        const float4 a1 = *(const float4*)(A + (size_t)(row0 + lr + 64) * 256 + k0 + lc);
        const float4 w0 = *(const float4*)(W + (size_t)(col0 + lr) * 256 + k0 + lc);
        const float4 w1 = *(const float4*)(W + (size_t)(col0 + lr + 64) * 256 + k0 + lc);
        __syncthreads();
        As[lc + 0][lr] = a0.x; As[lc + 1][lr] = a0.y; As[lc + 2][lr] = a0.z; As[lc + 3][lr] = a0.w;
        As[lc + 0][lr + 64] = a1.x; As[lc + 1][lr + 64] = a1.y; As[lc + 2][lr + 64] = a1.z; As[lc + 3][lr + 64] = a1.w;
        Bs[lc + 0][lr] = w0.x; Bs[lc + 1][lr] = w0.y; Bs[lc + 2][lr] = w0.z; Bs[lc + 3][lr] = w0.w;
        Bs[lc + 0][lr + 64] = w1.x; Bs[lc + 1][lr + 64] = w1.y; Bs[lc + 2][lr + 64] = w1.z; Bs[lc + 3][lr + 64] = w1.w;
        __syncthreads();
#pragma unroll
        for (int kk = 0; kk < 16; kk++) {
            const float4 alo = *(const float4*)&As[kk][ty * 8];
            const float4 ahi = *(const float4*)&As[kk][ty * 8 + 4];
            const float4 blo = *(const float4*)&Bs[kk][tx * 8];
            const float4 bhi = *(const float4*)&Bs[kk][tx * 8 + 4];
            const float av[8] = {alo.x, alo.y, alo.z, alo.w, ahi.x, ahi.y, ahi.z, ahi.w};
            const float bv[8] = {blo.x, blo.y, blo.z, blo.w, bhi.x, bhi.y, bhi.z, bhi.w};
#pragma unroll
            for (int r = 0; r < 8; r++)
#pragma unroll
                for (int c = 0; c < 8; c++)
                    acc[r][c] = fmaf(av[r], bv[c], acc[r][c]);
        }
    }
#pragma unroll
    for (int r = 0; r < 8; r++) {
        const int gr = row0 + ty * 8 + r;
        const int gc = col0 + tx * 8;
        float4 v0, v1;
        v0.x = acc[r][0] + bias[gc + 0]; v0.y = acc[r][1] + bias[gc + 1];
        v0.z = acc[r][2] + bias[gc + 2]; v0.w = acc[r][3] + bias[gc + 3];
        v1.x = acc[r][4] + bias[gc + 4]; v1.y = acc[r][5] + bias[gc + 5];
        v1.z = acc[r][6] + bias[gc + 6]; v1.w = acc[r][7] + bias[gc + 7];
        if (resid) {
            const float4 r0 = *(const float4*)(resid + (size_t)gr * 256 + gc);
            const float4 r1 = *(const float4*)(resid + (size_t)gr * 256 + gc + 4);
            v0.x += r0.x; v0.y += r0.y; v0.z += r0.z; v0.w += r0.w;
            v1.x += r1.x; v1.y += r1.y; v1.z += r1.z; v1.w += r1.w;
        }
        *(float4*)(C + (size_t)gr * 256 + gc) = v0;
        *(float4*)(C + (size_t)gr * 256 + gc + 4) = v1;
    }
}

__global__ __launch_bounds__(256) void qkv_gemm(
    const float* __restrict__ x,
    const float* __restrict__ Wq, const float* __restrict__ Wk, const float* __restrict__ Wv,
    const float* __restrict__ bq, const float* __restrict__ bk, const float* __restrict__ bv,
    float* __restrict__ Q, float* __restrict__ K, float* __restrict__ V)
{
    const int which = blockIdx.z;
    const float* W = which == 0 ? Wq : (which == 1 ? Wk : Wv);
    const float* b = which == 0 ? bq : (which == 1 ? bk : bv);
    float* C = which == 0 ? Q : (which == 1 ? K : V);
    gemm_body(x, W, b, nullptr, C, blockIdx.x, blockIdx.y);
}

__global__ __launch_bounds__(256) void out_gemm(
    const float* __restrict__ A, const float* __restrict__ Wo,
    const float* __restrict__ bo, const float* __restrict__ x,
    float* __restrict__ H)
{
    gemm_body(A, Wo, bo, x, H, blockIdx.x, blockIdx.y);
}

// ---------------------------------------------------------------------------
// Column sum of V -> S[256]
// ---------------------------------------------------------------------------
__global__ __launch_bounds__(256) void colsum(const float* __restrict__ V, float* __restrict__ S)
{
    const int t = threadIdx.x;
    const int r0 = blockIdx.x * 16;
    float s = 0.f;
#pragma unroll
    for (int r = 0; r < 16; r++) s += V[(size_t)(r0 + r) * 256 + t];
    atomicAdd(&S[t], s);
}

// ---------------------------------------------------------------------------
// Fully fused sparse attention. One block (256 thr, 4 waves) per row i.
//  stage A: stream adj row (float4, coalesced), ballot-scan compact -> lj[]
//  stage B: wave-per-edge (4-edge ILP): load K row AND V row (float4/lane),
//           dot + 4x shfl_xor (16-lane head groups; every lane gets its head's
//           score), w = expf(s)-1 per lane, num4 += w*v, den += w.
//  stage C: cross-wave LDS reduce, out = (num + S) / (den + 4096).
// ---------------------------------------------------------------------------
__global__ __launch_bounds__(256) void attn_fused(
    const float* __restrict__ Q, const float* __restrict__ K,
    const float* __restrict__ V, const float* __restrict__ adj,
    const float* __restrict__ S, float* __restrict__ out)
{
    __shared__ unsigned short lj[ECAP];
    __shared__ float pnum[4][256];
    __shared__ float pden[4][4];
    __shared__ int cnt;

    const int i = blockIdx.x;
    const int tid = threadIdx.x;
    const int wave = tid >> 6;
    const int lane = tid & 63;

    if (tid == 0) cnt = 0;
    __syncthreads();

    // ---- stage A: compact adjacency row ----
    const float4* __restrict__ arow = (const float4*)(adj + (size_t)i * NN);
#pragma unroll
    for (int t = 0; t < 4; t++) {
        const float4 a = arow[t * 256 + tid];
        const int j0 = (t * 256 + tid) * 4;
        const int c = (a.x != 0.f) + (a.y != 0.f) + (a.z != 0.f) + (a.w != 0.f);
        int off = c;
#pragma unroll
        for (int s = 1; s < 64; s <<= 1) {
            const int v = __shfl_up(off, s);
            if (lane >= s) off += v;
        }
        int base = 0;
        if (lane == 63) base = atomicAdd(&cnt, off);
        base = __shfl(base, 63);
        int p = base + off - c;
        if (a.x != 0.f && p < ECAP) lj[p++] = (unsigned short)(j0 + 0);
        if (a.y != 0.f && p < ECAP) lj[p++] = (unsigned short)(j0 + 1);
        if (a.z != 0.f && p < ECAP) lj[p++] = (unsigned short)(j0 + 2);
        if (a.w != 0.f && p < ECAP) lj[p++] = (unsigned short)(j0 + 3);
    }
    __syncthreads();
    const int m = min(cnt, ECAP);

    // ---- stage B: fused QK + PV over edges ----
    const float4 qraw = ((const float4*)(Q + (size_t)i * 256))[lane];
    const float4 qv = {qraw.x * 0.125f, qraw.y * 0.125f, qraw.z * 0.125f, qraw.w * 0.125f};
    float nx = 0.f, ny = 0.f, nz = 0.f, nw = 0.f, den = 0.f;

    for (int e0 = wave * 4; e0 < m; e0 += 16) {
        int jj[4];
#pragma unroll
        for (int u = 0; u < 4; u++)
            jj[u] = (e0 + u < m) ? (int)lj[e0 + u] : (int)lj[e0];
        float4 kv[4], vv[4];
#pragma unroll
        for (int u = 0; u < 4; u++) {
            kv[u] = ((const float4*)(K + (size_t)jj[u] * 256))[lane];
            vv[u] = ((const float4*)(V + (size_t)jj[u] * 256))[lane];
        }
#pragma unroll
        for (int u = 0; u < 4; u++) {
            float d = (kv[u].x * qv.x + kv[u].y * qv.y) + (kv[u].z * qv.z + kv[u].w * qv.w);
            d += __shfl_xor(d, 1);
            d += __shfl_xor(d, 2);
            d += __shfl_xor(d, 4);
            d += __shfl_xor(d, 8);
            float w = expf(d) - 1.f;
            if (e0 + u >= m) w = 0.f;
            nx = fmaf(w, vv[u].x, nx); ny = fmaf(w, vv[u].y, ny);
            nz = fmaf(w, vv[u].z, nz); nw = fmaf(w, vv[u].w, nw);
            den += w;
        }
    }

    // ---- stage C: cross-wave reduce + output ----
    pnum[wave][lane * 4 + 0] = nx;
    pnum[wave][lane * 4 + 1] = ny;
    pnum[wave][lane * 4 + 2] = nz;
    pnum[wave][lane * 4 + 3] = nw;
    if ((lane & 15) == 0) pden[wave][lane >> 4] = den;
    __syncthreads();

    const int head = tid >> 6;
    const float dn = (pden[0][head] + pden[1][head]) + (pden[2][head] + pden[3][head]) + 4096.0f;
    const float nm = (pnum[0][tid] + pnum[1][tid]) + (pnum[2][tid] + pnum[3][tid]) + S[tid];
    out[(size_t)i * 256 + tid] = nm / dn;
}

// ---------------------------------------------------------------------------
// Row LayerNorm: 4 rows per block (wave per row), 256 dims each.
// ---------------------------------------------------------------------------
__global__ __launch_bounds__(256) void ln_kernel(
    const float* __restrict__ H, const float* __restrict__ gamma,
    const float* __restrict__ beta, float* __restrict__ out)
{
    const int row = blockIdx.x * 4 + (threadIdx.x >> 6);
    const int lane = threadIdx.x & 63;
    const float4 v = ((const float4*)(H + (size_t)row * 256))[lane];
    float s = (v.x + v.y) + (v.z + v.w);
#pragma unroll
    for (int o = 1; o < 64; o <<= 1) s += __shfl_xor(s, o);
    const float mu = s * (1.f / 256.f);
    const float dx = v.x - mu, dy = v.y - mu, dz = v.z - mu, dw = v.w - mu;
    float sq = (dx * dx + dy * dy) + (dz * dz + dw * dw);
#pragma unroll
    for (int o = 1; o < 64; o <<= 1) sq += __shfl_xor(sq, o);
    const float rstd = rsqrtf(sq * (1.f / 256.f) + 1e-5f);
    const float4 g = ((const float4*)gamma)[lane];
    const float4 b = ((const float4*)beta)[lane];
    float4 o4;
    o4.x = dx * rstd * g.x + b.x;
    o4.y = dy * rstd * g.y + b.y;
    o4.z = dz * rstd * g.z + b.z;
    o4.w = dw * rstd * g.w + b.w;
    ((float4*)(out + (size_t)row * 256))[lane] = o4;
}

// ---------------------------------------------------------------------------
extern "C" void kernel_launch(void* const* d_in, const int* in_sizes, int n_in,
                              void* d_out, int out_size, void* d_ws, size_t ws_size,
                              hipStream_t stream)
{
    const float* x     = (const float*)d_in[0];
    const float* adj   = (const float*)d_in[1];
    const float* Wq    = (const float*)d_in[2];
    const float* bq    = (const float*)d_in[3];
    const float* Wk    = (const float*)d_in[4];
    const float* bk    = (const float*)d_in[5];
    const float* Wv    = (const float*)d_in[6];
    const float* bv    = (const float*)d_in[7];
    const float* Wo    = (const float*)d_in[8];
    const float* bo    = (const float*)d_in[9];
    const float* gamma = (const float*)d_in[10];
    const float* beta  = (const float*)d_in[11];

    float* ws = (float*)d_ws;
    const size_t NM = (size_t)NN * DIMV;   // 1M floats
    float* Qb = ws;
    float* Kb = ws + NM;
    float* Vb = ws + 2 * NM;
    float* AT = ws + 3 * NM;
    float* S  = ws + 4 * NM;   // 256 floats
    float* H  = Qb;            // reuse Q buffer after attention

    hipMemsetAsync(S, 0, 256 * sizeof(float), stream);
    qkv_gemm<<<dim3(32, 2, 3), 256, 0, stream>>>(x, Wq, Wk, Wv, bq, bk, bv, Qb, Kb, Vb);
    colsum<<<256, 256, 0, stream>>>(Vb, S);
    attn_fused<<<NN, 256, 0, stream>>>(Qb, Kb, Vb, adj, S, AT);
    out_gemm<<<dim3(32, 2, 1), 256, 0, stream>>>(AT, Wo, bo, x, H);
    ln_kernel<<<1024, 256, 0, stream>>>(H, gamma, beta, (float*)d_out);
}